// Round 19
// baseline (300.500 us; speedup 1.0000x reference)
//
#include <hip/hip_runtime.h>
#include <hip/hip_bf16.h>
#include <stdint.h>

// Problem constants
#define B_    8
#define N_    2048
#define M_    8192
#define C_    512
#define CSK   256
#define CIN   768
#define H1C   512
#define H2C   256
#define NCOL  65536     // B_*M_
typedef unsigned short u16;
typedef __attribute__((ext_vector_type(8))) short  s16x8;
typedef __attribute__((ext_vector_type(4))) float  f32x4;

// ---- bf16 helpers ----
__device__ inline u16 f2bf(float f) {            // RNE bit-trick (cold paths)
    unsigned u = __float_as_uint(f);
    unsigned r = (u + 0x7fffu + ((u >> 16) & 1u)) >> 16;
    return (u16)r;
}
__device__ inline u16 f2bf_hw(float f) {         // HW v_cvt
    __hip_bfloat16 h = __float2bfloat16(f);
    u16 u; __builtin_memcpy(&u, &h, 2);
    return u;
}
__device__ inline unsigned pk2bf(float lo, float hi) {  // HW v_cvt_pk_bf16_f32
    __hip_bfloat162 r = __float22bfloat162_rn(make_float2(lo, hi));
    unsigned u; __builtin_memcpy(&u, &r, 4);
    return u;
}
__device__ inline float bflo(unsigned u) { return __uint_as_float(u << 16); }
__device__ inline float bfhi(unsigned u) { return __uint_as_float(u & 0xffff0000u); }

// ---------------------------------------------------------------------------
// f32 -> bf16 bulk convert
// ---------------------------------------------------------------------------
__global__ __launch_bounds__(256) void cvt_bf16_k(const float* __restrict__ in,
                                                  u16* __restrict__ out, int n4) {
    const int i = blockIdx.x * 256 + threadIdx.x;
    if (i >= n4) return;
    const float4 v = *(const float4*)(in + (size_t)i * 4);
    u16 o[4] = {f2bf(v.x), f2bf(v.y), f2bf(v.z), f2bf(v.w)};
    *(uint2*)(out + (size_t)i * 4) = *(uint2*)o;
}

// ---------------------------------------------------------------------------
// 3-NN (round-12 validated: exact ordering, surrogate s = r^2 - 2 q.r)
// ---------------------------------------------------------------------------
__device__ inline void ins3(float d, int n,
                            float& d0, int& i0, float& d1, int& i1,
                            float& d2, int& i2) {
    const bool lt0 = d < d0, lt1 = d < d1, lt2 = d < d2;
    const float nd2 = lt1 ? d1 : (lt2 ? d : d2);
    const int   ni2 = lt1 ? i1 : (lt2 ? n : i2);
    const float nd1 = lt0 ? d0 : (lt1 ? d : d1);
    const int   ni1 = lt0 ? i0 : (lt1 ? n : i1);
    const float nd0 = lt0 ? d : d0;
    const int   ni0 = lt0 ? n : i0;
    d0 = nd0; d1 = nd1; d2 = nd2; i0 = ni0; i1 = ni1; i2 = ni2;
}

__global__ __launch_bounds__(256) void knn_kernel(const float* __restrict__ pos,
                                                  const float* __restrict__ pos_skip,
                                                  int* __restrict__ idx_out,
                                                  float* __restrict__ w_out) {
    __shared__ float rpx[N_], rpy[N_], rpz[N_], rr2[N_];
    const int b = blockIdx.y;
    const int tid = threadIdx.x;
    for (int t = tid; t < N_ * 3; t += 256) {
        const float v = pos[(size_t)b * N_ * 3 + t];
        const int n = t / 3, k = t - n * 3;
        if (k == 0) rpx[n] = v; else if (k == 1) rpy[n] = v; else rpz[n] = v;
    }
    __syncthreads();
    for (int n = tid; n < N_; n += 256)
        rr2[n] = rpx[n] * rpx[n] + rpy[n] * rpy[n] + rpz[n] * rpz[n];
    __syncthreads();

    const int q = tid >> 3;
    const int part = tid & 7;
    const int m = blockIdx.x * 32 + q;
    const size_t qoff = ((size_t)b * M_ + m) * 3;
    const float qx = pos_skip[qoff], qy = pos_skip[qoff + 1], qz = pos_skip[qoff + 2];
    const float q2x = -2.0f * qx, q2y = -2.0f * qy, q2z = -2.0f * qz;
    const float qq = qx * qx + qy * qy + qz * qz;

    float d0 = 1e30f, d1 = 1e30f, d2 = 1e30f;
    int i0 = 0, i1 = 0, i2 = 0;
#pragma unroll 4
    for (int i = 0; i < 64; ++i) {
        const int n = part * 4 + i * 32;
        const float4 xx = *(const float4*)&rpx[n];
        const float4 yy = *(const float4*)&rpy[n];
        const float4 zz = *(const float4*)&rpz[n];
        const float4 ww = *(const float4*)&rr2[n];
        const float s0 = fmaf(xx.x, q2x, fmaf(yy.x, q2y, fmaf(zz.x, q2z, ww.x)));
        const float s1 = fmaf(xx.y, q2x, fmaf(yy.y, q2y, fmaf(zz.y, q2z, ww.y)));
        const float s2 = fmaf(xx.z, q2x, fmaf(yy.z, q2y, fmaf(zz.z, q2z, ww.z)));
        const float s3 = fmaf(xx.w, q2x, fmaf(yy.w, q2y, fmaf(zz.w, q2z, ww.w)));
        ins3(s0, n + 0, d0, i0, d1, i1, d2, i2);
        ins3(s1, n + 1, d0, i0, d1, i1, d2, i2);
        ins3(s2, n + 2, d0, i0, d1, i1, d2, i2);
        ins3(s3, n + 3, d0, i0, d1, i1, d2, i2);
    }

#pragma unroll
    for (int xm = 1; xm <= 4; xm <<= 1) {
        const float od0 = __shfl_xor(d0, xm), od1 = __shfl_xor(d1, xm), od2 = __shfl_xor(d2, xm);
        const int   oi0 = __shfl_xor(i0, xm), oi1 = __shfl_xor(i1, xm), oi2 = __shfl_xor(i2, xm);
        ins3(od0, oi0, d0, i0, d1, i1, d2, i2);
        ins3(od1, oi1, d0, i0, d1, i1, d2, i2);
        ins3(od2, oi2, d0, i0, d1, i1, d2, i2);
    }

    if (part == 0) {
        const float dd0 = fmaxf(d0 + qq, 0.f);
        const float dd1 = fmaxf(d1 + qq, 0.f);
        const float dd2 = fmaxf(d2 + qq, 0.f);
        const float r0 = 1.0f / (sqrtf(dd0) + 1e-8f);
        const float r1 = 1.0f / (sqrtf(dd1) + 1e-8f);
        const float r2 = 1.0f / (sqrtf(dd2) + 1e-8f);
        const float inv = 1.0f / (r0 + r1 + r2);
        const size_t o = ((size_t)b * M_ + m) * 3;
        idx_out[o] = i0; idx_out[o + 1] = i1; idx_out[o + 2] = i2;
        w_out[o] = r0 * inv; w_out[o + 1] = r1 * inv; w_out[o + 2] = r2 * inv;
    }
}

// ---------------------------------------------------------------------------
// x [b][c][n] f32 -> xT [b][n][c] bf16
// ---------------------------------------------------------------------------
__global__ __launch_bounds__(256) void transpose_x(const float* __restrict__ x,
                                                   u16* __restrict__ xT) {
    __shared__ float t[32][33];
    const int tx = threadIdx.x & 31, ty = threadIdx.x >> 5;
    const int n0 = blockIdx.x * 32, c0 = blockIdx.y * 32, b = blockIdx.z;
#pragma unroll
    for (int r = 0; r < 4; ++r) {
        const int c = c0 + ty + r * 8;
        t[ty + r * 8][tx] = x[((size_t)b * C_ + c) * N_ + n0 + tx];
    }
    __syncthreads();
#pragma unroll
    for (int r = 0; r < 4; ++r) {
        const int n = n0 + ty + r * 8;
        xT[((size_t)b * N_ + n) * C_ + c0 + tx] = f2bf(t[tx][ty + r * 8]);
    }
}

// ---------------------------------------------------------------------------
// x_skip [b][c][m] f32 -> Feats[b*M+m][512+c] bf16 (CIN stride)
// ---------------------------------------------------------------------------
__global__ __launch_bounds__(256) void feats_skip(const float* __restrict__ xs,
                                                  u16* __restrict__ Feats) {
    __shared__ float t[32][33];
    const int tx = threadIdx.x & 31, ty = threadIdx.x >> 5;
    const int m0 = blockIdx.x * 32, c0 = blockIdx.y * 32, b = blockIdx.z;
#pragma unroll
    for (int r = 0; r < 4; ++r) {
        const int c = c0 + ty + r * 8;
        t[ty + r * 8][tx] = xs[((size_t)b * CSK + c) * M_ + m0 + tx];
    }
    __syncthreads();
#pragma unroll
    for (int r = 0; r < 4; ++r) {
        const int m = m0 + ty + r * 8;
        Feats[((size_t)b * M_ + m) * CIN + C_ + c0 + tx] = f2bf(t[tx][ty + r * 8]);
    }
}

// ---------------------------------------------------------------------------
// 3-NN interpolation -> Feats[:, 0:512] (HW cvt_pk; round-12-validated frame)
// ---------------------------------------------------------------------------
__device__ inline unsigned interp_pk(unsigned a, unsigned b, unsigned c,
                                     float w0, float w1, float w2) {
    const float lo = fmaf(w2, bflo(c), fmaf(w1, bflo(b), w0 * bflo(a)));
    const float hi = fmaf(w2, bfhi(c), fmaf(w1, bfhi(b), w0 * bfhi(a)));
    return pk2bf(lo, hi);
}
__global__ __launch_bounds__(256) void feats_interp(const u16* __restrict__ xT,
                                                    const int* __restrict__ idx,
                                                    const float* __restrict__ w,
                                                    u16* __restrict__ Feats) {
    const int b = blockIdx.y;
    const int lane = threadIdx.x & 63, wv = threadIdx.x >> 6;
    for (int t = 0; t < 16; ++t) {
        const int m = blockIdx.x * 64 + wv * 16 + t;
        const size_t col = (size_t)b * M_ + m;
        const int i0 = idx[col * 3], i1 = idx[col * 3 + 1], i2 = idx[col * 3 + 2];
        const float w0 = w[col * 3], w1 = w[col * 3 + 1], w2 = w[col * 3 + 2];
        const uint4 a = *(const uint4*)(xT + ((size_t)b * N_ + i0) * C_ + lane * 8);
        const uint4 c = *(const uint4*)(xT + ((size_t)b * N_ + i1) * C_ + lane * 8);
        const uint4 d = *(const uint4*)(xT + ((size_t)b * N_ + i2) * C_ + lane * 8);
        uint4 r;
        r.x = interp_pk(a.x, c.x, d.x, w0, w1, w2);
        r.y = interp_pk(a.y, c.y, d.y, w0, w1, w2);
        r.z = interp_pk(a.z, c.z, d.z, w0, w1, w2);
        r.w = interp_pk(a.w, c.w, d.w, w0, w1, w2);
        *(uint4*)(Feats + col * CIN + lane * 8) = r;
    }
}

// ---------------------------------------------------------------------------
// GEMM1 (round-12 VALIDATED 82.5 µs): BK=64, both-sides XOR swizzle,
// XCD-chunked grid, fused BN1 partials. A=W1b, B=Feats (CIN stride).
// ---------------------------------------------------------------------------
__device__ inline void stage64(u16* lds, const char* gbase, int ld2,
                               int lane, int wv) {
    const int slot = (lane & 7) ^ (lane >> 3);     // pre-swizzled source slot
#pragma unroll
    for (int jj = 0; jj < 4; ++jj) {
        const int chunk = jj * 4 + wv;             // 0..15 (1KB = 8 rows each)
        const int row = chunk * 8 + (lane >> 3);
        const char* g = gbase + (size_t)row * ld2 + slot * 16;
        __builtin_amdgcn_global_load_lds(
            (const __attribute__((address_space(1))) void*)g,
            (__attribute__((address_space(3))) void*)((char*)lds + chunk * 1024),
            16, 0, 0);
    }
}

__global__ __launch_bounds__(256) void gemm1(const u16* __restrict__ A,
                                             const u16* __restrict__ Bm,
                                             u16* __restrict__ H1,
                                             float* __restrict__ ps1,
                                             float* __restrict__ pq1) {
    __shared__ __attribute__((aligned(16))) u16 As[128 * 64];
    __shared__ __attribute__((aligned(16))) u16 Bs[128 * 64];
    __shared__ float lsum[2][128], lsq[2][128];
    const int tid = threadIdx.x;
    const int lane = tid & 63, wv = tid >> 6;
    const int wr = wv >> 1, wc = wv & 1;
    const int l15 = lane & 15, l4 = lane >> 4;
    const int v = (blockIdx.x & 7) * 256 + (blockIdx.x >> 3);
    const int rowblk = v & 3, colblk = v >> 2;
    const int rowM0 = rowblk * 128, colN0 = colblk * 128;
    f32x4 acc[4][4] = {};
    const char* Ab = (const char*)(A  + (size_t)rowM0 * CIN);
    const char* Bb = (const char*)(Bm + (size_t)colN0 * CIN);

    for (int kt = 0; kt < CIN / 64; ++kt) {
        stage64(As, Ab + kt * 128, CIN * 2, lane, wv);
        stage64(Bs, Bb + kt * 128, CIN * 2, lane, wv);
        __syncthreads();
#pragma unroll
        for (int ks = 0; ks < 2; ++ks) {
            s16x8 af[4], bfr[4];
#pragma unroll
            for (int i = 0; i < 4; ++i) {
                const int R = wr * 64 + i * 16 + l15;
                const int s = ((ks << 2) | l4) ^ (R & 7);
                af[i] = *(const s16x8*)((const char*)As + R * 128 + s * 16);
            }
#pragma unroll
            for (int j = 0; j < 4; ++j) {
                const int R = wc * 64 + j * 16 + l15;
                const int s = ((ks << 2) | l4) ^ (R & 7);
                bfr[j] = *(const s16x8*)((const char*)Bs + R * 128 + s * 16);
            }
#pragma unroll
            for (int i = 0; i < 4; ++i)
#pragma unroll
                for (int j = 0; j < 4; ++j)
                    acc[i][j] = __builtin_amdgcn_mfma_f32_16x16x32_bf16(bfr[j], af[i], acc[i][j], 0, 0, 0);
        }
        __syncthreads();
    }

    // store H1^T (bf16)
#pragma unroll
    for (int i = 0; i < 4; ++i) {
        const int o = rowM0 + wr * 64 + i * 16 + l15;
#pragma unroll
        for (int j = 0; j < 4; ++j) {
            const int colb = colN0 + wc * 64 + j * 16 + l4 * 4;
#pragma unroll
            for (int r = 0; r < 4; ++r)
                H1[(size_t)(colb + r) * H1C + o] = f2bf_hw(acc[i][j][r]);
        }
    }

    // BN1 partials (f32, deterministic)
#pragma unroll
    for (int i = 0; i < 4; ++i) {
        float s = 0.f, q = 0.f;
#pragma unroll
        for (int j = 0; j < 4; ++j)
#pragma unroll
            for (int r = 0; r < 4; ++r) {
                const float vv = acc[i][j][r];
                s += vv; q += vv * vv;
            }
        s += __shfl_xor(s, 16); q += __shfl_xor(q, 16);
        s += __shfl_xor(s, 32); q += __shfl_xor(q, 32);
        if ((lane & 48) == 0) {
            lsum[wc][wr * 64 + i * 16 + l15] = s;
            lsq [wc][wr * 64 + i * 16 + l15] = q;
        }
    }
    __syncthreads();
    if (tid < 128) {
        const float S = lsum[0][tid] + lsum[1][tid];
        const float Q = lsq[0][tid] + lsq[1][tid];
        ps1[(size_t)(rowM0 + tid) * 512 + colblk] = S;
        pq1[(size_t)(rowM0 + tid) * 512 + colblk] = Q;
    }
}

// ---------------------------------------------------------------------------
// BN1 final
// ---------------------------------------------------------------------------
__global__ __launch_bounds__(256) void bn1_final(const float* __restrict__ ps,
                                                 const float* __restrict__ pq,
                                                 const float* __restrict__ gamma,
                                                 const float* __restrict__ beta,
                                                 float* __restrict__ sc,
                                                 float* __restrict__ sh) {
    const int o = blockIdx.x;
    const int t = threadIdx.x;
    float S = ps[(size_t)o * 512 + t] + ps[(size_t)o * 512 + 256 + t];
    float Q = pq[(size_t)o * 512 + t] + pq[(size_t)o * 512 + 256 + t];
    __shared__ float rs[256], rq[256];
    rs[t] = S; rq[t] = Q;
    __syncthreads();
    for (int st = 128; st > 0; st >>= 1) {
        if (t < st) { rs[t] += rs[t + st]; rq[t] += rq[t + st]; }
        __syncthreads();
    }
    if (t == 0) {
        const float mean = rs[0] * (1.0f / NCOL);
        const float var  = fmaxf(rq[0] * (1.0f / NCOL) - mean * mean, 0.f);
        const float is   = rsqrtf(var + 1e-5f);
        const float s    = gamma[o] * is;
        sc[o] = s;
        sh[o] = beta[o] - mean * s;
    }
}

// ---------------------------------------------------------------------------
// GEMM2 with BN1 affine+leaky fused into reg-staged B (per-channel params
// at k0+kb). Fused BN2 partials. HW cvt_pk in xformB.
// ---------------------------------------------------------------------------
__device__ inline void stage2A(u16* dst, const u16* W2b, int k0,
                               int lane, int wv) {
#pragma unroll
    for (int h = 0; h < 2; ++h) {
        const int p_loc = h * 128 + wv * 16 + (lane >> 2);
        const u16* g = W2b + (size_t)p_loc * H1C + k0 + (lane & 3) * 8;
        __builtin_amdgcn_global_load_lds(
            (const __attribute__((address_space(1))) void*)g,
            (__attribute__((address_space(3))) void*)((char*)dst + (h * 512 + wv * 64) * 16),
            16, 0, 0);
    }
}

__global__ __launch_bounds__(512, 2) void gemm2(const u16* __restrict__ W2b,
                                                const u16* __restrict__ H1,
                                                const float* __restrict__ sc1,
                                                const float* __restrict__ sh1,
                                                float* __restrict__ out,
                                                float* __restrict__ ps2,
                                                float* __restrict__ pq2) {
    __shared__ __attribute__((aligned(16))) u16 As[2][256 * 32];
    __shared__ __attribute__((aligned(16))) u16 Bs[2][256 * 32];
    __shared__ float lsum[4][256], lsq[4][256];
    __shared__ float scs[512], shs[512];
    const int tid = threadIdx.x;
    const int lane = tid & 63, wv = tid >> 6;
    const int pgrp = wv & 1, cgrp = wv >> 1;
    const int l15 = lane & 15, l4 = lane >> 4;
    const int col0 = blockIdx.x * 256;
    const u16* Hb = H1 + (size_t)col0 * H1C;
    const int kb = (lane & 3) * 8;
    const int prow0 = wv * 16 + (lane >> 2);
    f32x4 acc[4][8] = {};

    scs[tid] = sc1[tid];
    shs[tid] = sh1[tid];

    stage2A(As[0], W2b, 0, lane, wv);
    uint4 nb0 = *(const uint4*)(Hb + (size_t)prow0 * H1C + kb);
    uint4 nb1 = *(const uint4*)(Hb + (size_t)(prow0 + 128) * H1C + kb);
    __syncthreads();   // scs/shs visible

    auto xformB = [&](int buf, uint4 b0, uint4 b1, int k0) {
        const f32x4 s0v = *(const f32x4*)&scs[k0 + kb];
        const f32x4 s1v = *(const f32x4*)&scs[k0 + kb + 4];
        const f32x4 h0v = *(const f32x4*)&shs[k0 + kb];
        const f32x4 h1v = *(const f32x4*)&shs[k0 + kb + 4];
        const float sv[8] = {s0v[0], s0v[1], s0v[2], s0v[3], s1v[0], s1v[1], s1v[2], s1v[3]};
        const float hv[8] = {h0v[0], h0v[1], h0v[2], h0v[3], h1v[0], h1v[1], h1v[2], h1v[3]};
        uint4 bw[2] = {b0, b1};
#pragma unroll
        for (int h = 0; h < 2; ++h) {
            unsigned uu[4] = {bw[h].x, bw[h].y, bw[h].z, bw[h].w};
            unsigned rr[4];
#pragma unroll
            for (int e = 0; e < 4; ++e) {
                float f0 = fmaf(bflo(uu[e]), sv[e * 2], hv[e * 2]);
                float f1 = fmaf(bfhi(uu[e]), sv[e * 2 + 1], hv[e * 2 + 1]);
                f0 = f0 >= 0.f ? f0 : 0.2f * f0;
                f1 = f1 >= 0.f ? f1 : 0.2f * f1;
                rr[e] = pk2bf(f0, f1);
            }
            *(uint4*)&Bs[buf][(size_t)(h * 512 + wv * 64 + lane) * 8] = make_uint4(rr[0], rr[1], rr[2], rr[3]);
        }
    };

    xformB(0, nb0, nb1, 0);
    __syncthreads();

    int cur = 0;
    for (int step = 0; step < 16; ++step) {
        if (step < 15) {
            const int k0 = (step + 1) * 32;
            stage2A(As[cur ^ 1], W2b, k0, lane, wv);
            nb0 = *(const uint4*)(Hb + (size_t)prow0 * H1C + k0 + kb);
            nb1 = *(const uint4*)(Hb + (size_t)(prow0 + 128) * H1C + k0 + kb);
        }
        const u16* Ac = As[cur];
        const u16* Bc = Bs[cur];
        s16x8 af[8], bfr[4];
#pragma unroll
        for (int pf = 0; pf < 8; ++pf)
            af[pf] = *(const s16x8*)&Ac[(pgrp * 128 + pf * 16 + l15) * 32 + l4 * 8];
#pragma unroll
        for (int cf = 0; cf < 4; ++cf)
            bfr[cf] = *(const s16x8*)&Bc[(cgrp * 64 + cf * 16 + l15) * 32 + l4 * 8];
#pragma unroll
        for (int cf = 0; cf < 4; ++cf)
#pragma unroll
            for (int pf = 0; pf < 8; ++pf)
                acc[cf][pf] = __builtin_amdgcn_mfma_f32_16x16x32_bf16(bfr[cf], af[pf], acc[cf][pf], 0, 0, 0);
        if (step < 15) {
            xformB(cur ^ 1, nb0, nb1, (step + 1) * 32);
        }
        __syncthreads();
        cur ^= 1;
    }

    const int bidx = col0 >> 13;
    const int mb   = col0 & (M_ - 1);
#pragma unroll
    for (int cf = 0; cf < 4; ++cf) {
#pragma unroll
        for (int pf = 0; pf < 8; ++pf) {
            const int p  = pgrp * 128 + pf * 16 + l15;
            const int mm = mb + cgrp * 64 + cf * 16 + l4 * 4;
            *(f32x4*)(out + (size_t)bidx * (H2C * M_) + (size_t)p * M_ + mm) = acc[cf][pf];
        }
    }

#pragma unroll
    for (int pf = 0; pf < 8; ++pf) {
        float s = 0.f, q = 0.f;
#pragma unroll
        for (int cf = 0; cf < 4; ++cf)
#pragma unroll
            for (int r = 0; r < 4; ++r) {
                const float vv = acc[cf][pf][r];
                s += vv; q += vv * vv;
            }
        s += __shfl_xor(s, 16); q += __shfl_xor(q, 16);
        s += __shfl_xor(s, 32); q += __shfl_xor(q, 32);
        if ((lane & 48) == 0) {
            lsum[cgrp][pgrp * 128 + pf * 16 + l15] = s;
            lsq [cgrp][pgrp * 128 + pf * 16 + l15] = q;
        }
    }
    __syncthreads();
    if (tid < 256) {
        const float S = lsum[0][tid] + lsum[1][tid] + lsum[2][tid] + lsum[3][tid];
        const float Q = lsq[0][tid] + lsq[1][tid] + lsq[2][tid] + lsq[3][tid];
        ps2[(size_t)tid * 256 + blockIdx.x] = S;
        pq2[(size_t)tid * 256 + blockIdx.x] = Q;
    }
}

// ---------------------------------------------------------------------------
// BN2 final
// ---------------------------------------------------------------------------
__global__ __launch_bounds__(256) void bn2_final(const float* __restrict__ ps,
                                                 const float* __restrict__ pq,
                                                 const float* __restrict__ gamma,
                                                 const float* __restrict__ beta,
                                                 float* __restrict__ sc,
                                                 float* __restrict__ sh) {
    const int p = blockIdx.x;
    const int t = threadIdx.x;
    float S = ps[(size_t)p * 256 + t];
    float Q = pq[(size_t)p * 256 + t];
    __shared__ float rs[256], rq[256];
    rs[t] = S; rq[t] = Q;
    __syncthreads();
    for (int st = 128; st > 0; st >>= 1) {
        if (t < st) { rs[t] += rs[t + st]; rq[t] += rq[t + st]; }
        __syncthreads();
    }
    if (t == 0) {
        const float mean = rs[0] * (1.0f / NCOL);
        const float var  = fmaxf(rq[0] * (1.0f / NCOL) - mean * mean, 0.f);
        const float is   = rsqrtf(var + 1e-5f);
        const float s    = gamma[p] * is;
        sc[p] = s;
        sh[p] = beta[p] - mean * s;
    }
}

// ---------------------------------------------------------------------------
// In-place BN2 affine + leaky on d_out
// ---------------------------------------------------------------------------
__global__ __launch_bounds__(256) void bn_apply2(float* __restrict__ out,
                                                 const float* __restrict__ sc,
                                                 const float* __restrict__ sh) {
    const size_t i = (size_t)blockIdx.x * 256 + threadIdx.x;
    const int p = (int)((i >> 13) & (H2C - 1));
    float v = out[i];
    v = fmaf(v, sc[p], sh[p]);
    out[i] = v >= 0.f ? v : 0.2f * v;
}

// ---------------------------------------------------------------------------
extern "C" void kernel_launch(void* const* d_in, const int* in_sizes, int n_in,
                              void* d_out, int out_size, void* d_ws, size_t ws_size,
                              hipStream_t stream) {
    const float* pos      = (const float*)d_in[0];
    const float* pos_skip = (const float*)d_in[1];
    const float* x        = (const float*)d_in[2];
    const float* x_skip   = (const float*)d_in[3];
    const float* W1       = (const float*)d_in[4];
    const float* gamma1   = (const float*)d_in[5];
    const float* beta1    = (const float*)d_in[6];
    const float* W2       = (const float*)d_in[7];
    const float* gamma2   = (const float*)d_in[8];
    const float* beta2    = (const float*)d_in[9];
    float* out = (float*)d_out;

    char* ws = (char*)d_ws;
    size_t off = 0;
    auto alloc = [&](size_t bytes) {
        void* p = ws + off;
        off = (off + bytes + 255) & ~(size_t)255;
        return p;
    };
    int*   idx   = (int*)  alloc((size_t)NCOL * 3 * sizeof(int));
    float* w     = (float*)alloc((size_t)NCOL * 3 * sizeof(float));
    u16*   xT    = (u16*)  alloc((size_t)B_ * N_ * C_ * sizeof(u16));     // 16.8 MB
    u16*   W1b   = (u16*)  alloc((size_t)H1C * CIN * sizeof(u16));
    u16*   W2b   = (u16*)  alloc((size_t)H2C * H1C * sizeof(u16));
    u16*   Feats = (u16*)  alloc((size_t)NCOL * CIN * sizeof(u16));       // 100.7 MB
    u16*   H1    = (u16*)  alloc((size_t)NCOL * H1C * sizeof(u16));       // 67.1 MB
    float* ps1   = (float*)alloc((size_t)H1C * 512 * sizeof(float));
    float* pq1   = (float*)alloc((size_t)H1C * 512 * sizeof(float));
    float* ps2   = (float*)alloc((size_t)H2C * 256 * sizeof(float));
    float* pq2   = (float*)alloc((size_t)H2C * 256 * sizeof(float));
    float* sc1   = (float*)alloc(H1C * sizeof(float));
    float* sh1   = (float*)alloc(H1C * sizeof(float));
    float* sc2   = (float*)alloc(H2C * sizeof(float));
    float* sh2   = (float*)alloc(H2C * sizeof(float));

    cvt_bf16_k<<<(H1C * CIN / 4 + 255) / 256, 256, 0, stream>>>(W1, W1b, H1C * CIN / 4);
    cvt_bf16_k<<<(H2C * H1C / 4 + 255) / 256, 256, 0, stream>>>(W2, W2b, H2C * H1C / 4);
    knn_kernel<<<dim3(M_ / 32, B_), 256, 0, stream>>>(pos, pos_skip, idx, w);
    transpose_x<<<dim3(N_ / 32, C_ / 32, B_), 256, 0, stream>>>(x, xT);
    feats_interp<<<dim3(M_ / 64, B_), 256, 0, stream>>>(xT, idx, w, Feats);
    feats_skip<<<dim3(M_ / 32, CSK / 32, B_), 256, 0, stream>>>(x_skip, Feats);
    gemm1<<<2048, 256, 0, stream>>>(W1b, Feats, H1, ps1, pq1);
    bn1_final<<<H1C, 256, 0, stream>>>(ps1, pq1, gamma1, beta1, sc1, sh1);
    gemm2<<<NCOL / 256, 512, 0, stream>>>(W2b, H1, sc1, sh1, out, ps2, pq2);
    bn2_final<<<H2C, 256, 0, stream>>>(ps2, pq2, gamma2, beta2, sc2, sh2);
    bn_apply2<<<(int)(((size_t)NCOL * H2C) / 256), 256, 0, stream>>>(out, sc2, sh2);
}

// Round 21
// 289.448 us; speedup vs baseline: 1.0382x; 1.0382x over previous
//
#include <hip/hip_runtime.h>
#include <hip/hip_bf16.h>
#include <stdint.h>

// Problem constants
#define B_    8
#define N_    2048
#define M_    8192
#define C_    512
#define CSK   256
#define CIN   768
#define H1C   512
#define H2C   256
#define NCOL  65536     // B_*M_
typedef unsigned short u16;
typedef __attribute__((ext_vector_type(8))) short  s16x8;
typedef __attribute__((ext_vector_type(4))) float  f32x4;

// ---- bf16 helpers ----
__device__ inline u16 f2bf(float f) {            // RNE bit-trick (cold paths)
    unsigned u = __float_as_uint(f);
    unsigned r = (u + 0x7fffu + ((u >> 16) & 1u)) >> 16;
    return (u16)r;
}
__device__ inline u16 f2bf_hw(float f) {         // HW v_cvt (hot paths)
    __hip_bfloat16 h = __float2bfloat16(f);
    u16 u; __builtin_memcpy(&u, &h, 2);
    return u;
}
__device__ inline unsigned pk2bf(float lo, float hi) {  // HW v_cvt_pk_bf16_f32
    __hip_bfloat162 r = __float22bfloat162_rn(make_float2(lo, hi));
    unsigned u; __builtin_memcpy(&u, &r, 4);
    return u;
}
__device__ inline float bflo(unsigned u) { return __uint_as_float(u << 16); }
__device__ inline float bfhi(unsigned u) { return __uint_as_float(u & 0xffff0000u); }

// ---------------------------------------------------------------------------
// f32 -> bf16 bulk convert
// ---------------------------------------------------------------------------
__global__ __launch_bounds__(256) void cvt_bf16_k(const float* __restrict__ in,
                                                  u16* __restrict__ out, int n4) {
    const int i = blockIdx.x * 256 + threadIdx.x;
    if (i >= n4) return;
    const float4 v = *(const float4*)(in + (size_t)i * 4);
    u16 o[4] = {f2bf(v.x), f2bf(v.y), f2bf(v.z), f2bf(v.w)};
    *(uint2*)(out + (size_t)i * 4) = *(uint2*)o;
}

// ---------------------------------------------------------------------------
// 3-NN (round-12 validated: exact ordering, surrogate s = r^2 - 2 q.r)
// ---------------------------------------------------------------------------
__device__ inline void ins3(float d, int n,
                            float& d0, int& i0, float& d1, int& i1,
                            float& d2, int& i2) {
    const bool lt0 = d < d0, lt1 = d < d1, lt2 = d < d2;
    const float nd2 = lt1 ? d1 : (lt2 ? d : d2);
    const int   ni2 = lt1 ? i1 : (lt2 ? n : i2);
    const float nd1 = lt0 ? d0 : (lt1 ? d : d1);
    const int   ni1 = lt0 ? i0 : (lt1 ? n : i1);
    const float nd0 = lt0 ? d : d0;
    const int   ni0 = lt0 ? n : i0;
    d0 = nd0; d1 = nd1; d2 = nd2; i0 = ni0; i1 = ni1; i2 = ni2;
}

__global__ __launch_bounds__(256) void knn_kernel(const float* __restrict__ pos,
                                                  const float* __restrict__ pos_skip,
                                                  int* __restrict__ idx_out,
                                                  float* __restrict__ w_out) {
    __shared__ float rpx[N_], rpy[N_], rpz[N_], rr2[N_];
    const int b = blockIdx.y;
    const int tid = threadIdx.x;
    for (int t = tid; t < N_ * 3; t += 256) {
        const float v = pos[(size_t)b * N_ * 3 + t];
        const int n = t / 3, k = t - n * 3;
        if (k == 0) rpx[n] = v; else if (k == 1) rpy[n] = v; else rpz[n] = v;
    }
    __syncthreads();
    for (int n = tid; n < N_; n += 256)
        rr2[n] = rpx[n] * rpx[n] + rpy[n] * rpy[n] + rpz[n] * rpz[n];
    __syncthreads();

    const int q = tid >> 3;
    const int part = tid & 7;
    const int m = blockIdx.x * 32 + q;
    const size_t qoff = ((size_t)b * M_ + m) * 3;
    const float qx = pos_skip[qoff], qy = pos_skip[qoff + 1], qz = pos_skip[qoff + 2];
    const float q2x = -2.0f * qx, q2y = -2.0f * qy, q2z = -2.0f * qz;
    const float qq = qx * qx + qy * qy + qz * qz;

    float d0 = 1e30f, d1 = 1e30f, d2 = 1e30f;
    int i0 = 0, i1 = 0, i2 = 0;
#pragma unroll 4
    for (int i = 0; i < 64; ++i) {
        const int n = part * 4 + i * 32;
        const float4 xx = *(const float4*)&rpx[n];
        const float4 yy = *(const float4*)&rpy[n];
        const float4 zz = *(const float4*)&rpz[n];
        const float4 ww = *(const float4*)&rr2[n];
        const float s0 = fmaf(xx.x, q2x, fmaf(yy.x, q2y, fmaf(zz.x, q2z, ww.x)));
        const float s1 = fmaf(xx.y, q2x, fmaf(yy.y, q2y, fmaf(zz.y, q2z, ww.y)));
        const float s2 = fmaf(xx.z, q2x, fmaf(yy.z, q2y, fmaf(zz.z, q2z, ww.z)));
        const float s3 = fmaf(xx.w, q2x, fmaf(yy.w, q2y, fmaf(zz.w, q2z, ww.w)));
        ins3(s0, n + 0, d0, i0, d1, i1, d2, i2);
        ins3(s1, n + 1, d0, i0, d1, i1, d2, i2);
        ins3(s2, n + 2, d0, i0, d1, i1, d2, i2);
        ins3(s3, n + 3, d0, i0, d1, i1, d2, i2);
    }

#pragma unroll
    for (int xm = 1; xm <= 4; xm <<= 1) {
        const float od0 = __shfl_xor(d0, xm), od1 = __shfl_xor(d1, xm), od2 = __shfl_xor(d2, xm);
        const int   oi0 = __shfl_xor(i0, xm), oi1 = __shfl_xor(i1, xm), oi2 = __shfl_xor(i2, xm);
        ins3(od0, oi0, d0, i0, d1, i1, d2, i2);
        ins3(od1, oi1, d0, i0, d1, i1, d2, i2);
        ins3(od2, oi2, d0, i0, d1, i1, d2, i2);
    }

    if (part == 0) {
        const float dd0 = fmaxf(d0 + qq, 0.f);
        const float dd1 = fmaxf(d1 + qq, 0.f);
        const float dd2 = fmaxf(d2 + qq, 0.f);
        const float r0 = 1.0f / (sqrtf(dd0) + 1e-8f);
        const float r1 = 1.0f / (sqrtf(dd1) + 1e-8f);
        const float r2 = 1.0f / (sqrtf(dd2) + 1e-8f);
        const float inv = 1.0f / (r0 + r1 + r2);
        const size_t o = ((size_t)b * M_ + m) * 3;
        idx_out[o] = i0; idx_out[o + 1] = i1; idx_out[o + 2] = i2;
        w_out[o] = r0 * inv; w_out[o + 1] = r1 * inv; w_out[o + 2] = r2 * inv;
    }
}

// ---------------------------------------------------------------------------
// x [b][c][n] f32 -> xT [b][n][c] bf16
// ---------------------------------------------------------------------------
__global__ __launch_bounds__(256) void transpose_x(const float* __restrict__ x,
                                                   u16* __restrict__ xT) {
    __shared__ float t[32][33];
    const int tx = threadIdx.x & 31, ty = threadIdx.x >> 5;
    const int n0 = blockIdx.x * 32, c0 = blockIdx.y * 32, b = blockIdx.z;
#pragma unroll
    for (int r = 0; r < 4; ++r) {
        const int c = c0 + ty + r * 8;
        t[ty + r * 8][tx] = x[((size_t)b * C_ + c) * N_ + n0 + tx];
    }
    __syncthreads();
#pragma unroll
    for (int r = 0; r < 4; ++r) {
        const int n = n0 + ty + r * 8;
        xT[((size_t)b * N_ + n) * C_ + c0 + tx] = f2bf(t[tx][ty + r * 8]);
    }
}

// ---------------------------------------------------------------------------
// x_skip [b][c][m] f32 -> FskipT [b*M+m][256] bf16 (compact)
// ---------------------------------------------------------------------------
__global__ __launch_bounds__(256) void feats_skip(const float* __restrict__ xs,
                                                  u16* __restrict__ Fsk) {
    __shared__ float t[32][33];
    const int tx = threadIdx.x & 31, ty = threadIdx.x >> 5;
    const int m0 = blockIdx.x * 32, c0 = blockIdx.y * 32, b = blockIdx.z;
#pragma unroll
    for (int r = 0; r < 4; ++r) {
        const int c = c0 + ty + r * 8;
        t[ty + r * 8][tx] = xs[((size_t)b * CSK + c) * M_ + m0 + tx];
    }
    __syncthreads();
#pragma unroll
    for (int r = 0; r < 4; ++r) {
        const int m = m0 + ty + r * 8;
        Fsk[((size_t)b * M_ + m) * CSK + c0 + tx] = f2bf(t[tx][ty + r * 8]);
    }
}

// ---------------------------------------------------------------------------
// interp helper: one packed u32 (2 bf16) from three sources, HW cvt_pk
// ---------------------------------------------------------------------------
__device__ inline unsigned interp_pk(unsigned a, unsigned b, unsigned c,
                                     float w0, float w1, float w2) {
    const float lo = fmaf(w2, bflo(c), fmaf(w1, bflo(b), w0 * bflo(a)));
    const float hi = fmaf(w2, bfhi(c), fmaf(w1, bfhi(b), w0 * bfhi(a)));
    return pk2bf(lo, hi);
}

// ---------------------------------------------------------------------------
// GEMM1, T14 pipelined, register-safe named gather state, fused 3-NN interp
// in B-staging (validated-best config: 292.3 us total).
// ---------------------------------------------------------------------------
__device__ inline void stage64(u16* lds, const char* gbase, int ld2,
                               int lane, int wv) {
    const int slot = (lane & 7) ^ (lane >> 3);     // pre-swizzled source slot
#pragma unroll
    for (int jj = 0; jj < 4; ++jj) {
        const int chunk = jj * 4 + wv;             // 0..15 (1KB = 8 rows each)
        const int row = chunk * 8 + (lane >> 3);
        const char* g = gbase + (size_t)row * ld2 + slot * 16;
        __builtin_amdgcn_global_load_lds(
            (const __attribute__((address_space(1))) void*)g,
            (__attribute__((address_space(3))) void*)((char*)lds + chunk * 1024),
            16, 0, 0);
    }
}

#define G1_GATHER(KT)                                                          \
    if ((KT) < 8) {                                                            \
        const int kk = (KT) * 64 + kk_off;                                     \
        gA0 = *(const uint4*)(xTb + (size_t)i00 * C_ + kk);                    \
        gC0 = *(const uint4*)(xTb + (size_t)i01 * C_ + kk);                    \
        gD0 = *(const uint4*)(xTb + (size_t)i02 * C_ + kk);                    \
        gA1 = *(const uint4*)(xTb + (size_t)i10 * C_ + kk);                    \
        gC1 = *(const uint4*)(xTb + (size_t)i11 * C_ + kk);                    \
        gD1 = *(const uint4*)(xTb + (size_t)i12 * C_ + kk);                    \
        gA2 = *(const uint4*)(xTb + (size_t)i20 * C_ + kk);                    \
        gC2 = *(const uint4*)(xTb + (size_t)i21 * C_ + kk);                    \
        gD2 = *(const uint4*)(xTb + (size_t)i22 * C_ + kk);                    \
        gA3 = *(const uint4*)(xTb + (size_t)i30 * C_ + kk);                    \
        gC3 = *(const uint4*)(xTb + (size_t)i31 * C_ + kk);                    \
        gD3 = *(const uint4*)(xTb + (size_t)i32 * C_ + kk);                    \
    } else {                                                                   \
        const int kk = ((KT) - 8) * 64 + kk_off;                               \
        gA0 = *(const uint4*)(Fsk + (size_t)(colN0 + prow      ) * CSK + kk);  \
        gA1 = *(const uint4*)(Fsk + (size_t)(colN0 + prow + 32 ) * CSK + kk);  \
        gA2 = *(const uint4*)(Fsk + (size_t)(colN0 + prow + 64 ) * CSK + kk);  \
        gA3 = *(const uint4*)(Fsk + (size_t)(colN0 + prow + 96 ) * CSK + kk);  \
    }

#define G1_INTERP1(BP, GA, GC, GD, W0, W1, W2)                                 \
    BP.x = interp_pk(GA.x, GC.x, GD.x, W0, W1, W2);                            \
    BP.y = interp_pk(GA.y, GC.y, GD.y, W0, W1, W2);                            \
    BP.z = interp_pk(GA.z, GC.z, GD.z, W0, W1, W2);                            \
    BP.w = interp_pk(GA.w, GC.w, GD.w, W0, W1, W2);

#define G1_WRITE(KT, BUF)                                                      \
    {                                                                          \
        char* bsb = (char*)Bs[BUF];                                            \
        if ((KT) < 8) {                                                        \
            uint4 bp0, bp1, bp2, bp3;                                          \
            G1_INTERP1(bp0, gA0, gC0, gD0, w00, w01, w02)                      \
            G1_INTERP1(bp1, gA1, gC1, gD1, w10, w11, w12)                      \
            G1_INTERP1(bp2, gA2, gC2, gD2, w20, w21, w22)                      \
            G1_INTERP1(bp3, gA3, gC3, gD3, w30, w31, w32)                      \
            *(uint4*)(bsb + bo0) = bp0;                                        \
            *(uint4*)(bsb + bo1) = bp1;                                        \
            *(uint4*)(bsb + bo2) = bp2;                                        \
            *(uint4*)(bsb + bo3) = bp3;                                        \
        } else {                                                               \
            *(uint4*)(bsb + bo0) = gA0;                                        \
            *(uint4*)(bsb + bo1) = gA1;                                        \
            *(uint4*)(bsb + bo2) = gA2;                                        \
            *(uint4*)(bsb + bo3) = gA3;                                        \
        }                                                                      \
    }

__global__ __launch_bounds__(256, 2) void gemm1(const u16* __restrict__ W1b,
                                                const u16* __restrict__ xT,
                                                const u16* __restrict__ Fsk,
                                                const int* __restrict__ idx,
                                                const float* __restrict__ w,
                                                u16* __restrict__ H1,
                                                float* __restrict__ ps1,
                                                float* __restrict__ pq1) {
    __shared__ __attribute__((aligned(16))) u16 As[2][128 * 64];
    __shared__ __attribute__((aligned(16))) u16 Bs[2][128 * 64];
    __shared__ float lsum[2][128], lsq[2][128];
    __shared__ int   sIdx[128][3];
    __shared__ float sW[128][3];
    const int tid = threadIdx.x;
    const int lane = tid & 63, wv = tid >> 6;
    const int wr = wv >> 1, wc = wv & 1;
    const int l15 = lane & 15, l4 = lane >> 4;
    const int v = (blockIdx.x & 7) * 256 + (blockIdx.x >> 3);
    const int rowblk = v & 3, colblk = v >> 2;
    const int rowM0 = rowblk * 128, colN0 = colblk * 128;
    const int b = colN0 >> 13;
    f32x4 acc[4][4] = {};
    const char* Ab = (const char*)(W1b + (size_t)rowM0 * CIN);
    const u16* xTb = xT + (size_t)b * N_ * C_;

    for (int t = tid; t < 384; t += 256) {
        const int rr = t / 3, kk = t - rr * 3;
        const size_t gi = ((size_t)colN0 + rr) * 3 + kk;
        sIdx[rr][kk] = idx[gi];
        sW[rr][kk]   = w[gi];
    }
    __syncthreads();   // sIdx/sW ready

    const int prow = tid >> 3;                 // 0..31 (row group)
    const int slot = tid & 7;                  // 16B slot within 64-k row
    const int kk_off = slot * 8;
    const int i00 = sIdx[prow][0],      i01 = sIdx[prow][1],      i02 = sIdx[prow][2];
    const int i10 = sIdx[prow + 32][0], i11 = sIdx[prow + 32][1], i12 = sIdx[prow + 32][2];
    const int i20 = sIdx[prow + 64][0], i21 = sIdx[prow + 64][1], i22 = sIdx[prow + 64][2];
    const int i30 = sIdx[prow + 96][0], i31 = sIdx[prow + 96][1], i32 = sIdx[prow + 96][2];
    const float w00 = sW[prow][0],      w01 = sW[prow][1],      w02 = sW[prow][2];
    const float w10 = sW[prow + 32][0], w11 = sW[prow + 32][1], w12 = sW[prow + 32][2];
    const float w20 = sW[prow + 64][0], w21 = sW[prow + 64][1], w22 = sW[prow + 64][2];
    const float w30 = sW[prow + 96][0], w31 = sW[prow + 96][1], w32 = sW[prow + 96][2];
    const int swz = slot ^ (prow & 7);
    const int bo0 = (prow      ) * 128 + swz * 16;
    const int bo1 = (prow + 32 ) * 128 + swz * 16;
    const int bo2 = (prow + 64 ) * 128 + swz * 16;
    const int bo3 = (prow + 96 ) * 128 + swz * 16;

    uint4 gA0, gA1, gA2, gA3, gC0, gC1, gC2, gC3, gD0, gD1, gD2, gD3;

    stage64(As[0], Ab + 0, CIN * 2, lane, wv);
    G1_GATHER(0)
    G1_WRITE(0, 0)
    __syncthreads();

    int cur = 0;
    for (int kt = 0; kt < CIN / 64; ++kt) {
        if (kt < CIN / 64 - 1) {
            stage64(As[cur ^ 1], Ab + (kt + 1) * 128, CIN * 2, lane, wv);
            G1_GATHER(kt + 1)
        }
        const u16* Ac = As[cur];
        const u16* Bc = Bs[cur];
#pragma unroll
        for (int ks = 0; ks < 2; ++ks) {
            s16x8 af[4], bfr[4];
#pragma unroll
            for (int i = 0; i < 4; ++i) {
                const int R = wr * 64 + i * 16 + l15;
                const int s = ((ks << 2) | l4) ^ (R & 7);
                af[i] = *(const s16x8*)((const char*)Ac + R * 128 + s * 16);
            }
#pragma unroll
            for (int j = 0; j < 4; ++j) {
                const int R = wc * 64 + j * 16 + l15;
                const int s = ((ks << 2) | l4) ^ (R & 7);
                bfr[j] = *(const s16x8*)((const char*)Bc + R * 128 + s * 16);
            }
#pragma unroll
            for (int i = 0; i < 4; ++i)
#pragma unroll
                for (int j = 0; j < 4; ++j)
                    acc[i][j] = __builtin_amdgcn_mfma_f32_16x16x32_bf16(bfr[j], af[i], acc[i][j], 0, 0, 0);
        }
        if (kt < CIN / 64 - 1) G1_WRITE(kt + 1, cur ^ 1)
        __syncthreads();
        cur ^= 1;
    }

    // store H1^T (bf16) via HW cvt
#pragma unroll
    for (int i = 0; i < 4; ++i) {
        const int o = rowM0 + wr * 64 + i * 16 + l15;
#pragma unroll
        for (int j = 0; j < 4; ++j) {
            const int colb = colN0 + wc * 64 + j * 16 + l4 * 4;
#pragma unroll
            for (int r = 0; r < 4; ++r)
                H1[(size_t)(colb + r) * H1C + o] = f2bf_hw(acc[i][j][r]);
        }
    }

    // BN1 partials (f32, deterministic)
#pragma unroll
    for (int i = 0; i < 4; ++i) {
        float s = 0.f, q = 0.f;
#pragma unroll
        for (int j = 0; j < 4; ++j)
#pragma unroll
            for (int r = 0; r < 4; ++r) {
                const float vv = acc[i][j][r];
                s += vv; q += vv * vv;
            }
        s += __shfl_xor(s, 16); q += __shfl_xor(q, 16);
        s += __shfl_xor(s, 32); q += __shfl_xor(q, 32);
        if ((lane & 48) == 0) {
            lsum[wc][wr * 64 + i * 16 + l15] = s;
            lsq [wc][wr * 64 + i * 16 + l15] = q;
        }
    }
    __syncthreads();
    if (tid < 128) {
        const float S = lsum[0][tid] + lsum[1][tid];
        const float Q = lsq[0][tid] + lsq[1][tid];
        ps1[(size_t)(rowM0 + tid) * 512 + colblk] = S;
        pq1[(size_t)(rowM0 + tid) * 512 + colblk] = Q;
    }
}

// ---------------------------------------------------------------------------
// BN1 final
// ---------------------------------------------------------------------------
__global__ __launch_bounds__(256) void bn1_final(const float* __restrict__ ps,
                                                 const float* __restrict__ pq,
                                                 const float* __restrict__ gamma,
                                                 const float* __restrict__ beta,
                                                 float* __restrict__ sc,
                                                 float* __restrict__ sh) {
    const int o = blockIdx.x;
    const int t = threadIdx.x;
    float S = ps[(size_t)o * 512 + t] + ps[(size_t)o * 512 + 256 + t];
    float Q = pq[(size_t)o * 512 + t] + pq[(size_t)o * 512 + 256 + t];
    __shared__ float rs[256], rq[256];
    rs[t] = S; rq[t] = Q;
    __syncthreads();
    for (int st = 128; st > 0; st >>= 1) {
        if (t < st) { rs[t] += rs[t + st]; rq[t] += rq[t + st]; }
        __syncthreads();
    }
    if (t == 0) {
        const float mean = rs[0] * (1.0f / NCOL);
        const float var  = fmaxf(rq[0] * (1.0f / NCOL) - mean * mean, 0.f);
        const float is   = rsqrtf(var + 1e-5f);
        const float s    = gamma[o] * is;
        sc[o] = s;
        sh[o] = beta[o] - mean * s;
    }
}

// ---------------------------------------------------------------------------
// GEMM2 with BN1 affine+leaky fused into reg-staged B (per-channel params
// at k0+kb). Fused BN2 partials. HW cvt_pk in xformB.
// ---------------------------------------------------------------------------
__device__ inline void stage2A(u16* dst, const u16* W2b, int k0,
                               int lane, int wv) {
#pragma unroll
    for (int h = 0; h < 2; ++h) {
        const int p_loc = h * 128 + wv * 16 + (lane >> 2);
        const u16* g = W2b + (size_t)p_loc * H1C + k0 + (lane & 3) * 8;
        __builtin_amdgcn_global_load_lds(
            (const __attribute__((address_space(1))) void*)g,
            (__attribute__((address_space(3))) void*)((char*)dst + (h * 512 + wv * 64) * 16),
            16, 0, 0);
    }
}

__global__ __launch_bounds__(512, 2) void gemm2(const u16* __restrict__ W2b,
                                                const u16* __restrict__ H1,
                                                const float* __restrict__ sc1,
                                                const float* __restrict__ sh1,
                                                float* __restrict__ out,
                                                float* __restrict__ ps2,
                                                float* __restrict__ pq2) {
    __shared__ __attribute__((aligned(16))) u16 As[2][256 * 32];
    __shared__ __attribute__((aligned(16))) u16 Bs[2][256 * 32];
    __shared__ float lsum[4][256], lsq[4][256];
    __shared__ float scs[512], shs[512];
    const int tid = threadIdx.x;
    const int lane = tid & 63, wv = tid >> 6;
    const int pgrp = wv & 1, cgrp = wv >> 1;
    const int l15 = lane & 15, l4 = lane >> 4;
    const int col0 = blockIdx.x * 256;
    const u16* Hb = H1 + (size_t)col0 * H1C;
    const int kb = (lane & 3) * 8;
    const int prow0 = wv * 16 + (lane >> 2);
    f32x4 acc[4][8] = {};

    scs[tid] = sc1[tid];
    shs[tid] = sh1[tid];

    stage2A(As[0], W2b, 0, lane, wv);
    uint4 nb0 = *(const uint4*)(Hb + (size_t)prow0 * H1C + kb);
    uint4 nb1 = *(const uint4*)(Hb + (size_t)(prow0 + 128) * H1C + kb);
    __syncthreads();   // scs/shs visible

    auto xformB = [&](int buf, uint4 b0, uint4 b1, int k0) {
        const f32x4 s0v = *(const f32x4*)&scs[k0 + kb];
        const f32x4 s1v = *(const f32x4*)&scs[k0 + kb + 4];
        const f32x4 h0v = *(const f32x4*)&shs[k0 + kb];
        const f32x4 h1v = *(const f32x4*)&shs[k0 + kb + 4];
        const float sv[8] = {s0v[0], s0v[1], s0v[2], s0v[3], s1v[0], s1v[1], s1v[2], s1v[3]};
        const float hv[8] = {h0v[0], h0v[1], h0v[2], h0v[3], h1v[0], h1v[1], h1v[2], h1v[3]};
        uint4 bw[2] = {b0, b1};
#pragma unroll
        for (int h = 0; h < 2; ++h) {
            unsigned uu[4] = {bw[h].x, bw[h].y, bw[h].z, bw[h].w};
            unsigned rr[4];
#pragma unroll
            for (int e = 0; e < 4; ++e) {
                float f0 = fmaf(bflo(uu[e]), sv[e * 2], hv[e * 2]);
                float f1 = fmaf(bfhi(uu[e]), sv[e * 2 + 1], hv[e * 2 + 1]);
                f0 = f0 >= 0.f ? f0 : 0.2f * f0;
                f1 = f1 >= 0.f ? f1 : 0.2f * f1;
                rr[e] = pk2bf(f0, f1);
            }
            *(uint4*)&Bs[buf][(size_t)(h * 512 + wv * 64 + lane) * 8] = make_uint4(rr[0], rr[1], rr[2], rr[3]);
        }
    };

    xformB(0, nb0, nb1, 0);
    __syncthreads();

    int cur = 0;
    for (int step = 0; step < 16; ++step) {
        if (step < 15) {
            const int k0 = (step + 1) * 32;
            stage2A(As[cur ^ 1], W2b, k0, lane, wv);
            nb0 = *(const uint4*)(Hb + (size_t)prow0 * H1C + k0 + kb);
            nb1 = *(const uint4*)(Hb + (size_t)(prow0 + 128) * H1C + k0 + kb);
        }
        const u16* Ac = As[cur];
        const u16* Bc = Bs[cur];
        s16x8 af[8], bfr[4];
#pragma unroll
        for (int pf = 0; pf < 8; ++pf)
            af[pf] = *(const s16x8*)&Ac[(pgrp * 128 + pf * 16 + l15) * 32 + l4 * 8];
#pragma unroll
        for (int cf = 0; cf < 4; ++cf)
            bfr[cf] = *(const s16x8*)&Bc[(cgrp * 64 + cf * 16 + l15) * 32 + l4 * 8];
#pragma unroll
        for (int cf = 0; cf < 4; ++cf)
#pragma unroll
            for (int pf = 0; pf < 8; ++pf)
                acc[cf][pf] = __builtin_amdgcn_mfma_f32_16x16x32_bf16(bfr[cf], af[pf], acc[cf][pf], 0, 0, 0);
        if (step < 15) {
            xformB(cur ^ 1, nb0, nb1, (step + 1) * 32);
        }
        __syncthreads();
        cur ^= 1;
    }

    const int bidx = col0 >> 13;
    const int mb   = col0 & (M_ - 1);
#pragma unroll
    for (int cf = 0; cf < 4; ++cf) {
#pragma unroll
        for (int pf = 0; pf < 8; ++pf) {
            const int p  = pgrp * 128 + pf * 16 + l15;
            const int mm = mb + cgrp * 64 + cf * 16 + l4 * 4;
            *(f32x4*)(out + (size_t)bidx * (H2C * M_) + (size_t)p * M_ + mm) = acc[cf][pf];
        }
    }

#pragma unroll
    for (int pf = 0; pf < 8; ++pf) {
        float s = 0.f, q = 0.f;
#pragma unroll
        for (int cf = 0; cf < 4; ++cf)
#pragma unroll
            for (int r = 0; r < 4; ++r) {
                const float vv = acc[cf][pf][r];
                s += vv; q += vv * vv;
            }
        s += __shfl_xor(s, 16); q += __shfl_xor(q, 16);
        s += __shfl_xor(s, 32); q += __shfl_xor(q, 32);
        if ((lane & 48) == 0) {
            lsum[cgrp][pgrp * 128 + pf * 16 + l15] = s;
            lsq [cgrp][pgrp * 128 + pf * 16 + l15] = q;
        }
    }
    __syncthreads();
    if (tid < 256) {
        const float S = lsum[0][tid] + lsum[1][tid] + lsum[2][tid] + lsum[3][tid];
        const float Q = lsq[0][tid] + lsq[1][tid] + lsq[2][tid] + lsq[3][tid];
        ps2[(size_t)tid * 256 + blockIdx.x] = S;
        pq2[(size_t)tid * 256 + blockIdx.x] = Q;
    }
}

// ---------------------------------------------------------------------------
// BN2 final
// ---------------------------------------------------------------------------
__global__ __launch_bounds__(256) void bn2_final(const float* __restrict__ ps,
                                                 const float* __restrict__ pq,
                                                 const float* __restrict__ gamma,
                                                 const float* __restrict__ beta,
                                                 float* __restrict__ sc,
                                                 float* __restrict__ sh) {
    const int p = blockIdx.x;
    const int t = threadIdx.x;
    float S = ps[(size_t)p * 256 + t];
    float Q = pq[(size_t)p * 256 + t];
    __shared__ float rs[256], rq[256];
    rs[t] = S; rq[t] = Q;
    __syncthreads();
    for (int st = 128; st > 0; st >>= 1) {
        if (t < st) { rs[t] += rs[t + st]; rq[t] += rq[t + st]; }
        __syncthreads();
    }
    if (t == 0) {
        const float mean = rs[0] * (1.0f / NCOL);
        const float var  = fmaxf(rq[0] * (1.0f / NCOL) - mean * mean, 0.f);
        const float is   = rsqrtf(var + 1e-5f);
        const float s    = gamma[p] * is;
        sc[p] = s;
        sh[p] = beta[p] - mean * s;
    }
}

// ---------------------------------------------------------------------------
// In-place BN2 affine + leaky on d_out
// ---------------------------------------------------------------------------
__global__ __launch_bounds__(256) void bn_apply2(float* __restrict__ out,
                                                 const float* __restrict__ sc,
                                                 const float* __restrict__ sh) {
    const size_t i = (size_t)blockIdx.x * 256 + threadIdx.x;
    const int p = (int)((i >> 13) & (H2C - 1));
    float v = out[i];
    v = fmaf(v, sc[p], sh[p]);
    out[i] = v >= 0.f ? v : 0.2f * v;
}

// ---------------------------------------------------------------------------
extern "C" void kernel_launch(void* const* d_in, const int* in_sizes, int n_in,
                              void* d_out, int out_size, void* d_ws, size_t ws_size,
                              hipStream_t stream) {
    const float* pos      = (const float*)d_in[0];
    const float* pos_skip = (const float*)d_in[1];
    const float* x        = (const float*)d_in[2];
    const float* x_skip   = (const float*)d_in[3];
    const float* W1       = (const float*)d_in[4];
    const float* gamma1   = (const float*)d_in[5];
    const float* beta1    = (const float*)d_in[6];
    const float* W2       = (const float*)d_in[7];
    const float* gamma2   = (const float*)d_in[8];
    const float* beta2    = (const float*)d_in[9];
    float* out = (float*)d_out;

    char* ws = (char*)d_ws;
    size_t off = 0;
    auto alloc = [&](size_t bytes) {
        void* p = ws + off;
        off = (off + bytes + 255) & ~(size_t)255;
        return p;
    };
    int*   idx   = (int*)  alloc((size_t)NCOL * 3 * sizeof(int));
    float* w     = (float*)alloc((size_t)NCOL * 3 * sizeof(float));
    u16*   xT    = (u16*)  alloc((size_t)B_ * N_ * C_ * sizeof(u16));     // 16.8 MB
    u16*   W1b   = (u16*)  alloc((size_t)H1C * CIN * sizeof(u16));
    u16*   W2b   = (u16*)  alloc((size_t)H2C * H1C * sizeof(u16));
    u16*   Fsk   = (u16*)  alloc((size_t)NCOL * CSK * sizeof(u16));       // 33.5 MB
    u16*   H1    = (u16*)  alloc((size_t)NCOL * H1C * sizeof(u16));       // 67.1 MB
    float* ps1   = (float*)alloc((size_t)H1C * 512 * sizeof(float));
    float* pq1   = (float*)alloc((size_t)H1C * 512 * sizeof(float));
    float* ps2   = (float*)alloc((size_t)H2C * 256 * sizeof(float));
    float* pq2   = (float*)alloc((size_t)H2C * 256 * sizeof(float));
    float* sc1   = (float*)alloc(H1C * sizeof(float));
    float* sh1   = (float*)alloc(H1C * sizeof(float));
    float* sc2   = (float*)alloc(H2C * sizeof(float));
    float* sh2   = (float*)alloc(H2C * sizeof(float));

    cvt_bf16_k<<<(H1C * CIN / 4 + 255) / 256, 256, 0, stream>>>(W1, W1b, H1C * CIN / 4);
    cvt_bf16_k<<<(H2C * H1C / 4 + 255) / 256, 256, 0, stream>>>(W2, W2b, H2C * H1C / 4);
    knn_kernel<<<dim3(M_ / 32, B_), 256, 0, stream>>>(pos, pos_skip, idx, w);
    transpose_x<<<dim3(N_ / 32, C_ / 32, B_), 256, 0, stream>>>(x, xT);
    feats_skip<<<dim3(M_ / 32, CSK / 32, B_), 256, 0, stream>>>(x_skip, Fsk);
    gemm1<<<2048, 256, 0, stream>>>(W1b, xT, Fsk, idx, w, H1, ps1, pq1);
    bn1_final<<<H1C, 256, 0, stream>>>(ps1, pq1, gamma1, beta1, sc1, sh1);
    gemm2<<<NCOL / 256, 512, 0, stream>>>(W2b, H1, sc1, sh1, out, ps2, pq2);
    bn2_final<<<H2C, 256, 0, stream>>>(ps2, pq2, gamma2, beta2, sc2, sh2);
    bn_apply2<<<(int)(((size_t)NCOL * H2C) / 256), 256, 0, stream>>>(out, sc2, sh2);
}

// Round 22
// 288.038 us; speedup vs baseline: 1.0433x; 1.0049x over previous
//
#include <hip/hip_runtime.h>
#include <hip/hip_bf16.h>
#include <stdint.h>

// Problem constants
#define B_    8
#define N_    2048
#define M_    8192
#define C_    512
#define CSK   256
#define CIN   768
#define H1C   512
#define H2C   256
#define NCOL  65536     // B_*M_
typedef unsigned short u16;
typedef __attribute__((ext_vector_type(8))) short  s16x8;
typedef __attribute__((ext_vector_type(4))) float  f32x4;

// ---- bf16 helpers ----
__device__ inline u16 f2bf(float f) {            // RNE bit-trick (cold paths)
    unsigned u = __float_as_uint(f);
    unsigned r = (u + 0x7fffu + ((u >> 16) & 1u)) >> 16;
    return (u16)r;
}
__device__ inline u16 f2bf_hw(float f) {         // HW v_cvt (hot paths)
    __hip_bfloat16 h = __float2bfloat16(f);
    u16 u; __builtin_memcpy(&u, &h, 2);
    return u;
}
__device__ inline unsigned pk2bf(float lo, float hi) {  // HW v_cvt_pk_bf16_f32
    __hip_bfloat162 r = __float22bfloat162_rn(make_float2(lo, hi));
    unsigned u; __builtin_memcpy(&u, &r, 4);
    return u;
}
__device__ inline float bflo(unsigned u) { return __uint_as_float(u << 16); }
__device__ inline float bfhi(unsigned u) { return __uint_as_float(u & 0xffff0000u); }

// ---------------------------------------------------------------------------
// f32 -> bf16 bulk convert
// ---------------------------------------------------------------------------
__global__ __launch_bounds__(256) void cvt_bf16_k(const float* __restrict__ in,
                                                  u16* __restrict__ out, int n4) {
    const int i = blockIdx.x * 256 + threadIdx.x;
    if (i >= n4) return;
    const float4 v = *(const float4*)(in + (size_t)i * 4);
    u16 o[4] = {f2bf(v.x), f2bf(v.y), f2bf(v.z), f2bf(v.w)};
    *(uint2*)(out + (size_t)i * 4) = *(uint2*)o;
}

// ---------------------------------------------------------------------------
// 3-NN (round-12 validated: exact ordering, surrogate s = r^2 - 2 q.r)
// ---------------------------------------------------------------------------
__device__ inline void ins3(float d, int n,
                            float& d0, int& i0, float& d1, int& i1,
                            float& d2, int& i2) {
    const bool lt0 = d < d0, lt1 = d < d1, lt2 = d < d2;
    const float nd2 = lt1 ? d1 : (lt2 ? d : d2);
    const int   ni2 = lt1 ? i1 : (lt2 ? n : i2);
    const float nd1 = lt0 ? d0 : (lt1 ? d : d1);
    const int   ni1 = lt0 ? i0 : (lt1 ? n : i1);
    const float nd0 = lt0 ? d : d0;
    const int   ni0 = lt0 ? n : i0;
    d0 = nd0; d1 = nd1; d2 = nd2; i0 = ni0; i1 = ni1; i2 = ni2;
}

__global__ __launch_bounds__(256) void knn_kernel(const float* __restrict__ pos,
                                                  const float* __restrict__ pos_skip,
                                                  int* __restrict__ idx_out,
                                                  float* __restrict__ w_out) {
    __shared__ float rpx[N_], rpy[N_], rpz[N_], rr2[N_];
    const int b = blockIdx.y;
    const int tid = threadIdx.x;
    for (int t = tid; t < N_ * 3; t += 256) {
        const float v = pos[(size_t)b * N_ * 3 + t];
        const int n = t / 3, k = t - n * 3;
        if (k == 0) rpx[n] = v; else if (k == 1) rpy[n] = v; else rpz[n] = v;
    }
    __syncthreads();
    for (int n = tid; n < N_; n += 256)
        rr2[n] = rpx[n] * rpx[n] + rpy[n] * rpy[n] + rpz[n] * rpz[n];
    __syncthreads();

    const int q = tid >> 3;
    const int part = tid & 7;
    const int m = blockIdx.x * 32 + q;
    const size_t qoff = ((size_t)b * M_ + m) * 3;
    const float qx = pos_skip[qoff], qy = pos_skip[qoff + 1], qz = pos_skip[qoff + 2];
    const float q2x = -2.0f * qx, q2y = -2.0f * qy, q2z = -2.0f * qz;
    const float qq = qx * qx + qy * qy + qz * qz;

    float d0 = 1e30f, d1 = 1e30f, d2 = 1e30f;
    int i0 = 0, i1 = 0, i2 = 0;
#pragma unroll 4
    for (int i = 0; i < 64; ++i) {
        const int n = part * 4 + i * 32;
        const float4 xx = *(const float4*)&rpx[n];
        const float4 yy = *(const float4*)&rpy[n];
        const float4 zz = *(const float4*)&rpz[n];
        const float4 ww = *(const float4*)&rr2[n];
        const float s0 = fmaf(xx.x, q2x, fmaf(yy.x, q2y, fmaf(zz.x, q2z, ww.x)));
        const float s1 = fmaf(xx.y, q2x, fmaf(yy.y, q2y, fmaf(zz.y, q2z, ww.y)));
        const float s2 = fmaf(xx.z, q2x, fmaf(yy.z, q2y, fmaf(zz.z, q2z, ww.z)));
        const float s3 = fmaf(xx.w, q2x, fmaf(yy.w, q2y, fmaf(zz.w, q2z, ww.w)));
        ins3(s0, n + 0, d0, i0, d1, i1, d2, i2);
        ins3(s1, n + 1, d0, i0, d1, i1, d2, i2);
        ins3(s2, n + 2, d0, i0, d1, i1, d2, i2);
        ins3(s3, n + 3, d0, i0, d1, i1, d2, i2);
    }

#pragma unroll
    for (int xm = 1; xm <= 4; xm <<= 1) {
        const float od0 = __shfl_xor(d0, xm), od1 = __shfl_xor(d1, xm), od2 = __shfl_xor(d2, xm);
        const int   oi0 = __shfl_xor(i0, xm), oi1 = __shfl_xor(i1, xm), oi2 = __shfl_xor(i2, xm);
        ins3(od0, oi0, d0, i0, d1, i1, d2, i2);
        ins3(od1, oi1, d0, i0, d1, i1, d2, i2);
        ins3(od2, oi2, d0, i0, d1, i1, d2, i2);
    }

    if (part == 0) {
        const float dd0 = fmaxf(d0 + qq, 0.f);
        const float dd1 = fmaxf(d1 + qq, 0.f);
        const float dd2 = fmaxf(d2 + qq, 0.f);
        const float r0 = 1.0f / (sqrtf(dd0) + 1e-8f);
        const float r1 = 1.0f / (sqrtf(dd1) + 1e-8f);
        const float r2 = 1.0f / (sqrtf(dd2) + 1e-8f);
        const float inv = 1.0f / (r0 + r1 + r2);
        const size_t o = ((size_t)b * M_ + m) * 3;
        idx_out[o] = i0; idx_out[o + 1] = i1; idx_out[o + 2] = i2;
        w_out[o] = r0 * inv; w_out[o + 1] = r1 * inv; w_out[o + 2] = r2 * inv;
    }
}

// ---------------------------------------------------------------------------
// x [b][c][n] f32 -> xT [b][n][c] bf16
// ---------------------------------------------------------------------------
__global__ __launch_bounds__(256) void transpose_x(const float* __restrict__ x,
                                                   u16* __restrict__ xT) {
    __shared__ float t[32][33];
    const int tx = threadIdx.x & 31, ty = threadIdx.x >> 5;
    const int n0 = blockIdx.x * 32, c0 = blockIdx.y * 32, b = blockIdx.z;
#pragma unroll
    for (int r = 0; r < 4; ++r) {
        const int c = c0 + ty + r * 8;
        t[ty + r * 8][tx] = x[((size_t)b * C_ + c) * N_ + n0 + tx];
    }
    __syncthreads();
#pragma unroll
    for (int r = 0; r < 4; ++r) {
        const int n = n0 + ty + r * 8;
        xT[((size_t)b * N_ + n) * C_ + c0 + tx] = f2bf(t[tx][ty + r * 8]);
    }
}

// ---------------------------------------------------------------------------
// x_skip [b][c][m] f32 -> FskipT [b*M+m][256] bf16 (compact)
// ---------------------------------------------------------------------------
__global__ __launch_bounds__(256) void feats_skip(const float* __restrict__ xs,
                                                  u16* __restrict__ Fsk) {
    __shared__ float t[32][33];
    const int tx = threadIdx.x & 31, ty = threadIdx.x >> 5;
    const int m0 = blockIdx.x * 32, c0 = blockIdx.y * 32, b = blockIdx.z;
#pragma unroll
    for (int r = 0; r < 4; ++r) {
        const int c = c0 + ty + r * 8;
        t[ty + r * 8][tx] = xs[((size_t)b * CSK + c) * M_ + m0 + tx];
    }
    __syncthreads();
#pragma unroll
    for (int r = 0; r < 4; ++r) {
        const int m = m0 + ty + r * 8;
        Fsk[((size_t)b * M_ + m) * CSK + c0 + tx] = f2bf(t[tx][ty + r * 8]);
    }
}

// ---------------------------------------------------------------------------
// interp helper: one packed u32 (2 bf16) from three sources, HW cvt_pk
// ---------------------------------------------------------------------------
__device__ inline unsigned interp_pk(unsigned a, unsigned b, unsigned c,
                                     float w0, float w1, float w2) {
    const float lo = fmaf(w2, bflo(c), fmaf(w1, bflo(b), w0 * bflo(a)));
    const float hi = fmaf(w2, bfhi(c), fmaf(w1, bfhi(b), w0 * bfhi(a)));
    return pk2bf(lo, hi);
}

// ---------------------------------------------------------------------------
// GEMM1, T14 pipelined, register-safe named gather state, fused 3-NN interp
// in B-staging (validated-best config).
// ---------------------------------------------------------------------------
__device__ inline void stage64(u16* lds, const char* gbase, int ld2,
                               int lane, int wv) {
    const int slot = (lane & 7) ^ (lane >> 3);     // pre-swizzled source slot
#pragma unroll
    for (int jj = 0; jj < 4; ++jj) {
        const int chunk = jj * 4 + wv;             // 0..15 (1KB = 8 rows each)
        const int row = chunk * 8 + (lane >> 3);
        const char* g = gbase + (size_t)row * ld2 + slot * 16;
        __builtin_amdgcn_global_load_lds(
            (const __attribute__((address_space(1))) void*)g,
            (__attribute__((address_space(3))) void*)((char*)lds + chunk * 1024),
            16, 0, 0);
    }
}

#define G1_GATHER(KT)                                                          \
    if ((KT) < 8) {                                                            \
        const int kk = (KT) * 64 + kk_off;                                     \
        gA0 = *(const uint4*)(xTb + (size_t)i00 * C_ + kk);                    \
        gC0 = *(const uint4*)(xTb + (size_t)i01 * C_ + kk);                    \
        gD0 = *(const uint4*)(xTb + (size_t)i02 * C_ + kk);                    \
        gA1 = *(const uint4*)(xTb + (size_t)i10 * C_ + kk);                    \
        gC1 = *(const uint4*)(xTb + (size_t)i11 * C_ + kk);                    \
        gD1 = *(const uint4*)(xTb + (size_t)i12 * C_ + kk);                    \
        gA2 = *(const uint4*)(xTb + (size_t)i20 * C_ + kk);                    \
        gC2 = *(const uint4*)(xTb + (size_t)i21 * C_ + kk);                    \
        gD2 = *(const uint4*)(xTb + (size_t)i22 * C_ + kk);                    \
        gA3 = *(const uint4*)(xTb + (size_t)i30 * C_ + kk);                    \
        gC3 = *(const uint4*)(xTb + (size_t)i31 * C_ + kk);                    \
        gD3 = *(const uint4*)(xTb + (size_t)i32 * C_ + kk);                    \
    } else {                                                                   \
        const int kk = ((KT) - 8) * 64 + kk_off;                               \
        gA0 = *(const uint4*)(Fsk + (size_t)(colN0 + prow      ) * CSK + kk);  \
        gA1 = *(const uint4*)(Fsk + (size_t)(colN0 + prow + 32 ) * CSK + kk);  \
        gA2 = *(const uint4*)(Fsk + (size_t)(colN0 + prow + 64 ) * CSK + kk);  \
        gA3 = *(const uint4*)(Fsk + (size_t)(colN0 + prow + 96 ) * CSK + kk);  \
    }

#define G1_INTERP1(BP, GA, GC, GD, W0, W1, W2)                                 \
    BP.x = interp_pk(GA.x, GC.x, GD.x, W0, W1, W2);                            \
    BP.y = interp_pk(GA.y, GC.y, GD.y, W0, W1, W2);                            \
    BP.z = interp_pk(GA.z, GC.z, GD.z, W0, W1, W2);                            \
    BP.w = interp_pk(GA.w, GC.w, GD.w, W0, W1, W2);

#define G1_WRITE(KT, BUF)                                                      \
    {                                                                          \
        char* bsb = (char*)Bs[BUF];                                            \
        if ((KT) < 8) {                                                        \
            uint4 bp0, bp1, bp2, bp3;                                          \
            G1_INTERP1(bp0, gA0, gC0, gD0, w00, w01, w02)                      \
            G1_INTERP1(bp1, gA1, gC1, gD1, w10, w11, w12)                      \
            G1_INTERP1(bp2, gA2, gC2, gD2, w20, w21, w22)                      \
            G1_INTERP1(bp3, gA3, gC3, gD3, w30, w31, w32)                      \
            *(uint4*)(bsb + bo0) = bp0;                                        \
            *(uint4*)(bsb + bo1) = bp1;                                        \
            *(uint4*)(bsb + bo2) = bp2;                                        \
            *(uint4*)(bsb + bo3) = bp3;                                        \
        } else {                                                               \
            *(uint4*)(bsb + bo0) = gA0;                                        \
            *(uint4*)(bsb + bo1) = gA1;                                        \
            *(uint4*)(bsb + bo2) = gA2;                                        \
            *(uint4*)(bsb + bo3) = gA3;                                        \
        }                                                                      \
    }

__global__ __launch_bounds__(256, 2) void gemm1(const u16* __restrict__ W1b,
                                                const u16* __restrict__ xT,
                                                const u16* __restrict__ Fsk,
                                                const int* __restrict__ idx,
                                                const float* __restrict__ w,
                                                u16* __restrict__ H1,
                                                float* __restrict__ ps1,
                                                float* __restrict__ pq1) {
    __shared__ __attribute__((aligned(16))) u16 As[2][128 * 64];
    __shared__ __attribute__((aligned(16))) u16 Bs[2][128 * 64];
    __shared__ float lsum[2][128], lsq[2][128];
    __shared__ int   sIdx[128][3];
    __shared__ float sW[128][3];
    const int tid = threadIdx.x;
    const int lane = tid & 63, wv = tid >> 6;
    const int wr = wv >> 1, wc = wv & 1;
    const int l15 = lane & 15, l4 = lane >> 4;
    const int v = (blockIdx.x & 7) * 256 + (blockIdx.x >> 3);
    const int rowblk = v & 3, colblk = v >> 2;
    const int rowM0 = rowblk * 128, colN0 = colblk * 128;
    const int b = colN0 >> 13;
    f32x4 acc[4][4] = {};
    const char* Ab = (const char*)(W1b + (size_t)rowM0 * CIN);
    const u16* xTb = xT + (size_t)b * N_ * C_;

    for (int t = tid; t < 384; t += 256) {
        const int rr = t / 3, kk = t - rr * 3;
        const size_t gi = ((size_t)colN0 + rr) * 3 + kk;
        sIdx[rr][kk] = idx[gi];
        sW[rr][kk]   = w[gi];
    }
    __syncthreads();   // sIdx/sW ready

    const int prow = tid >> 3;                 // 0..31 (row group)
    const int slot = tid & 7;                  // 16B slot within 64-k row
    const int kk_off = slot * 8;
    const int i00 = sIdx[prow][0],      i01 = sIdx[prow][1],      i02 = sIdx[prow][2];
    const int i10 = sIdx[prow + 32][0], i11 = sIdx[prow + 32][1], i12 = sIdx[prow + 32][2];
    const int i20 = sIdx[prow + 64][0], i21 = sIdx[prow + 64][1], i22 = sIdx[prow + 64][2];
    const int i30 = sIdx[prow + 96][0], i31 = sIdx[prow + 96][1], i32 = sIdx[prow + 96][2];
    const float w00 = sW[prow][0],      w01 = sW[prow][1],      w02 = sW[prow][2];
    const float w10 = sW[prow + 32][0], w11 = sW[prow + 32][1], w12 = sW[prow + 32][2];
    const float w20 = sW[prow + 64][0], w21 = sW[prow + 64][1], w22 = sW[prow + 64][2];
    const float w30 = sW[prow + 96][0], w31 = sW[prow + 96][1], w32 = sW[prow + 96][2];
    const int swz = slot ^ (prow & 7);
    const int bo0 = (prow      ) * 128 + swz * 16;
    const int bo1 = (prow + 32 ) * 128 + swz * 16;
    const int bo2 = (prow + 64 ) * 128 + swz * 16;
    const int bo3 = (prow + 96 ) * 128 + swz * 16;

    uint4 gA0, gA1, gA2, gA3, gC0, gC1, gC2, gC3, gD0, gD1, gD2, gD3;

    stage64(As[0], Ab + 0, CIN * 2, lane, wv);
    G1_GATHER(0)
    G1_WRITE(0, 0)
    __syncthreads();

    int cur = 0;
    for (int kt = 0; kt < CIN / 64; ++kt) {
        if (kt < CIN / 64 - 1) {
            stage64(As[cur ^ 1], Ab + (kt + 1) * 128, CIN * 2, lane, wv);
            G1_GATHER(kt + 1)
        }
        const u16* Ac = As[cur];
        const u16* Bc = Bs[cur];
#pragma unroll
        for (int ks = 0; ks < 2; ++ks) {
            s16x8 af[4], bfr[4];
#pragma unroll
            for (int i = 0; i < 4; ++i) {
                const int R = wr * 64 + i * 16 + l15;
                const int s = ((ks << 2) | l4) ^ (R & 7);
                af[i] = *(const s16x8*)((const char*)Ac + R * 128 + s * 16);
            }
#pragma unroll
            for (int j = 0; j < 4; ++j) {
                const int R = wc * 64 + j * 16 + l15;
                const int s = ((ks << 2) | l4) ^ (R & 7);
                bfr[j] = *(const s16x8*)((const char*)Bc + R * 128 + s * 16);
            }
#pragma unroll
            for (int i = 0; i < 4; ++i)
#pragma unroll
                for (int j = 0; j < 4; ++j)
                    acc[i][j] = __builtin_amdgcn_mfma_f32_16x16x32_bf16(bfr[j], af[i], acc[i][j], 0, 0, 0);
        }
        if (kt < CIN / 64 - 1) G1_WRITE(kt + 1, cur ^ 1)
        __syncthreads();
        cur ^= 1;
    }

    // store H1^T (bf16) via HW cvt
#pragma unroll
    for (int i = 0; i < 4; ++i) {
        const int o = rowM0 + wr * 64 + i * 16 + l15;
#pragma unroll
        for (int j = 0; j < 4; ++j) {
            const int colb = colN0 + wc * 64 + j * 16 + l4 * 4;
#pragma unroll
            for (int r = 0; r < 4; ++r)
                H1[(size_t)(colb + r) * H1C + o] = f2bf_hw(acc[i][j][r]);
        }
    }

    // BN1 partials (f32, deterministic)
#pragma unroll
    for (int i = 0; i < 4; ++i) {
        float s = 0.f, q = 0.f;
#pragma unroll
        for (int j = 0; j < 4; ++j)
#pragma unroll
            for (int r = 0; r < 4; ++r) {
                const float vv = acc[i][j][r];
                s += vv; q += vv * vv;
            }
        s += __shfl_xor(s, 16); q += __shfl_xor(q, 16);
        s += __shfl_xor(s, 32); q += __shfl_xor(q, 32);
        if ((lane & 48) == 0) {
            lsum[wc][wr * 64 + i * 16 + l15] = s;
            lsq [wc][wr * 64 + i * 16 + l15] = q;
        }
    }
    __syncthreads();
    if (tid < 128) {
        const float S = lsum[0][tid] + lsum[1][tid];
        const float Q = lsq[0][tid] + lsq[1][tid];
        ps1[(size_t)(rowM0 + tid) * 512 + colblk] = S;
        pq1[(size_t)(rowM0 + tid) * 512 + colblk] = Q;
    }
}

// ---------------------------------------------------------------------------
// BN1 final
// ---------------------------------------------------------------------------
__global__ __launch_bounds__(256) void bn1_final(const float* __restrict__ ps,
                                                 const float* __restrict__ pq,
                                                 const float* __restrict__ gamma,
                                                 const float* __restrict__ beta,
                                                 float* __restrict__ sc,
                                                 float* __restrict__ sh) {
    const int o = blockIdx.x;
    const int t = threadIdx.x;
    float S = ps[(size_t)o * 512 + t] + ps[(size_t)o * 512 + 256 + t];
    float Q = pq[(size_t)o * 512 + t] + pq[(size_t)o * 512 + 256 + t];
    __shared__ float rs[256], rq[256];
    rs[t] = S; rq[t] = Q;
    __syncthreads();
    for (int st = 128; st > 0; st >>= 1) {
        if (t < st) { rs[t] += rs[t + st]; rq[t] += rq[t + st]; }
        __syncthreads();
    }
    if (t == 0) {
        const float mean = rs[0] * (1.0f / NCOL);
        const float var  = fmaxf(rq[0] * (1.0f / NCOL) - mean * mean, 0.f);
        const float is   = rsqrtf(var + 1e-5f);
        const float s    = gamma[o] * is;
        sc[o] = s;
        sh[o] = beta[o] - mean * s;
    }
}

// ---------------------------------------------------------------------------
// GEMM2 with BN1 affine+leaky fused into reg-staged B (per-channel params
// at k0+kb). Fused BN2 partials. HW cvt_pk in xformB.
// ---------------------------------------------------------------------------
__device__ inline void stage2A(u16* dst, const u16* W2b, int k0,
                               int lane, int wv) {
#pragma unroll
    for (int h = 0; h < 2; ++h) {
        const int p_loc = h * 128 + wv * 16 + (lane >> 2);
        const u16* g = W2b + (size_t)p_loc * H1C + k0 + (lane & 3) * 8;
        __builtin_amdgcn_global_load_lds(
            (const __attribute__((address_space(1))) void*)g,
            (__attribute__((address_space(3))) void*)((char*)dst + (h * 512 + wv * 64) * 16),
            16, 0, 0);
    }
}

__global__ __launch_bounds__(512, 2) void gemm2(const u16* __restrict__ W2b,
                                                const u16* __restrict__ H1,
                                                const float* __restrict__ sc1,
                                                const float* __restrict__ sh1,
                                                float* __restrict__ out,
                                                float* __restrict__ ps2,
                                                float* __restrict__ pq2) {
    __shared__ __attribute__((aligned(16))) u16 As[2][256 * 32];
    __shared__ __attribute__((aligned(16))) u16 Bs[2][256 * 32];
    __shared__ float lsum[4][256], lsq[4][256];
    __shared__ float scs[512], shs[512];
    const int tid = threadIdx.x;
    const int lane = tid & 63, wv = tid >> 6;
    const int pgrp = wv & 1, cgrp = wv >> 1;
    const int l15 = lane & 15, l4 = lane >> 4;
    const int col0 = blockIdx.x * 256;
    const u16* Hb = H1 + (size_t)col0 * H1C;
    const int kb = (lane & 3) * 8;
    const int prow0 = wv * 16 + (lane >> 2);
    f32x4 acc[4][8] = {};

    scs[tid] = sc1[tid];
    shs[tid] = sh1[tid];

    stage2A(As[0], W2b, 0, lane, wv);
    uint4 nb0 = *(const uint4*)(Hb + (size_t)prow0 * H1C + kb);
    uint4 nb1 = *(const uint4*)(Hb + (size_t)(prow0 + 128) * H1C + kb);
    __syncthreads();   // scs/shs visible

    auto xformB = [&](int buf, uint4 b0, uint4 b1, int k0) {
        const f32x4 s0v = *(const f32x4*)&scs[k0 + kb];
        const f32x4 s1v = *(const f32x4*)&scs[k0 + kb + 4];
        const f32x4 h0v = *(const f32x4*)&shs[k0 + kb];
        const f32x4 h1v = *(const f32x4*)&shs[k0 + kb + 4];
        const float sv[8] = {s0v[0], s0v[1], s0v[2], s0v[3], s1v[0], s1v[1], s1v[2], s1v[3]};
        const float hv[8] = {h0v[0], h0v[1], h0v[2], h0v[3], h1v[0], h1v[1], h1v[2], h1v[3]};
        uint4 bw[2] = {b0, b1};
#pragma unroll
        for (int h = 0; h < 2; ++h) {
            unsigned uu[4] = {bw[h].x, bw[h].y, bw[h].z, bw[h].w};
            unsigned rr[4];
#pragma unroll
            for (int e = 0; e < 4; ++e) {
                float f0 = fmaf(bflo(uu[e]), sv[e * 2], hv[e * 2]);
                float f1 = fmaf(bfhi(uu[e]), sv[e * 2 + 1], hv[e * 2 + 1]);
                f0 = f0 >= 0.f ? f0 : 0.2f * f0;
                f1 = f1 >= 0.f ? f1 : 0.2f * f1;
                rr[e] = pk2bf(f0, f1);
            }
            *(uint4*)&Bs[buf][(size_t)(h * 512 + wv * 64 + lane) * 8] = make_uint4(rr[0], rr[1], rr[2], rr[3]);
        }
    };

    xformB(0, nb0, nb1, 0);
    __syncthreads();

    int cur = 0;
    for (int step = 0; step < 16; ++step) {
        if (step < 15) {
            const int k0 = (step + 1) * 32;
            stage2A(As[cur ^ 1], W2b, k0, lane, wv);
            nb0 = *(const uint4*)(Hb + (size_t)prow0 * H1C + k0 + kb);
            nb1 = *(const uint4*)(Hb + (size_t)(prow0 + 128) * H1C + k0 + kb);
        }
        const u16* Ac = As[cur];
        const u16* Bc = Bs[cur];
        s16x8 af[8], bfr[4];
#pragma unroll
        for (int pf = 0; pf < 8; ++pf)
            af[pf] = *(const s16x8*)&Ac[(pgrp * 128 + pf * 16 + l15) * 32 + l4 * 8];
#pragma unroll
        for (int cf = 0; cf < 4; ++cf)
            bfr[cf] = *(const s16x8*)&Bc[(cgrp * 64 + cf * 16 + l15) * 32 + l4 * 8];
#pragma unroll
        for (int cf = 0; cf < 4; ++cf)
#pragma unroll
            for (int pf = 0; pf < 8; ++pf)
                acc[cf][pf] = __builtin_amdgcn_mfma_f32_16x16x32_bf16(bfr[cf], af[pf], acc[cf][pf], 0, 0, 0);
        if (step < 15) {
            xformB(cur ^ 1, nb0, nb1, (step + 1) * 32);
        }
        __syncthreads();
        cur ^= 1;
    }

    const int bidx = col0 >> 13;
    const int mb   = col0 & (M_ - 1);
#pragma unroll
    for (int cf = 0; cf < 4; ++cf) {
#pragma unroll
        for (int pf = 0; pf < 8; ++pf) {
            const int p  = pgrp * 128 + pf * 16 + l15;
            const int mm = mb + cgrp * 64 + cf * 16 + l4 * 4;
            *(f32x4*)(out + (size_t)bidx * (H2C * M_) + (size_t)p * M_ + mm) = acc[cf][pf];
        }
    }

#pragma unroll
    for (int pf = 0; pf < 8; ++pf) {
        float s = 0.f, q = 0.f;
#pragma unroll
        for (int cf = 0; cf < 4; ++cf)
#pragma unroll
            for (int r = 0; r < 4; ++r) {
                const float vv = acc[cf][pf][r];
                s += vv; q += vv * vv;
            }
        s += __shfl_xor(s, 16); q += __shfl_xor(q, 16);
        s += __shfl_xor(s, 32); q += __shfl_xor(q, 32);
        if ((lane & 48) == 0) {
            lsum[cgrp][pgrp * 128 + pf * 16 + l15] = s;
            lsq [cgrp][pgrp * 128 + pf * 16 + l15] = q;
        }
    }
    __syncthreads();
    if (tid < 256) {
        const float S = lsum[0][tid] + lsum[1][tid] + lsum[2][tid] + lsum[3][tid];
        const float Q = lsq[0][tid] + lsq[1][tid] + lsq[2][tid] + lsq[3][tid];
        ps2[(size_t)tid * 256 + blockIdx.x] = S;
        pq2[(size_t)tid * 256 + blockIdx.x] = Q;
    }
}

// ---------------------------------------------------------------------------
// BN2 final
// ---------------------------------------------------------------------------
__global__ __launch_bounds__(256) void bn2_final(const float* __restrict__ ps,
                                                 const float* __restrict__ pq,
                                                 const float* __restrict__ gamma,
                                                 const float* __restrict__ beta,
                                                 float* __restrict__ sc,
                                                 float* __restrict__ sh) {
    const int p = blockIdx.x;
    const int t = threadIdx.x;
    float S = ps[(size_t)p * 256 + t];
    float Q = pq[(size_t)p * 256 + t];
    __shared__ float rs[256], rq[256];
    rs[t] = S; rq[t] = Q;
    __syncthreads();
    for (int st = 128; st > 0; st >>= 1) {
        if (t < st) { rs[t] += rs[t + st]; rq[t] += rq[t + st]; }
        __syncthreads();
    }
    if (t == 0) {
        const float mean = rs[0] * (1.0f / NCOL);
        const float var  = fmaxf(rq[0] * (1.0f / NCOL) - mean * mean, 0.f);
        const float is   = rsqrtf(var + 1e-5f);
        const float s    = gamma[p] * is;
        sc[p] = s;
        sh[p] = beta[p] - mean * s;
    }
}

// ---------------------------------------------------------------------------
// In-place BN2 affine + leaky on d_out
// ---------------------------------------------------------------------------
__global__ __launch_bounds__(256) void bn_apply2(float* __restrict__ out,
                                                 const float* __restrict__ sc,
                                                 const float* __restrict__ sh) {
    const size_t i = (size_t)blockIdx.x * 256 + threadIdx.x;
    const int p = (int)((i >> 13) & (H2C - 1));
    float v = out[i];
    v = fmaf(v, sc[p], sh[p]);
    out[i] = v >= 0.f ? v : 0.2f * v;
}

// ---------------------------------------------------------------------------
extern "C" void kernel_launch(void* const* d_in, const int* in_sizes, int n_in,
                              void* d_out, int out_size, void* d_ws, size_t ws_size,
                              hipStream_t stream) {
    const float* pos      = (const float*)d_in[0];
    const float* pos_skip = (const float*)d_in[1];
    const float* x        = (const float*)d_in[2];
    const float* x_skip   = (const float*)d_in[3];
    const float* W1       = (const float*)d_in[4];
    const float* gamma1   = (const float*)d_in[5];
    const float* beta1    = (const float*)d_in[6];
    const float* W2       = (const float*)d_in[7];
    const float* gamma2   = (const float*)d_in[8];
    const float* beta2    = (const float*)d_in[9];
    float* out = (float*)d_out;

    char* ws = (char*)d_ws;
    size_t off = 0;
    auto alloc = [&](size_t bytes) {
        void* p = ws + off;
        off = (off + bytes + 255) & ~(size_t)255;
        return p;
    };
    int*   idx   = (int*)  alloc((size_t)NCOL * 3 * sizeof(int));
    float* w     = (float*)alloc((size_t)NCOL * 3 * sizeof(float));
    u16*   xT    = (u16*)  alloc((size_t)B_ * N_ * C_ * sizeof(u16));     // 16.8 MB
    u16*   W1b   = (u16*)  alloc((size_t)H1C * CIN * sizeof(u16));
    u16*   W2b   = (u16*)  alloc((size_t)H2C * H1C * sizeof(u16));
    u16*   Fsk   = (u16*)  alloc((size_t)NCOL * CSK * sizeof(u16));       // 33.5 MB
    u16*   H1    = (u16*)  alloc((size_t)NCOL * H1C * sizeof(u16));       // 67.1 MB
    float* ps1   = (float*)alloc((size_t)H1C * 512 * sizeof(float));
    float* pq1   = (float*)alloc((size_t)H1C * 512 * sizeof(float));
    float* ps2   = (float*)alloc((size_t)H2C * 256 * sizeof(float));
    float* pq2   = (float*)alloc((size_t)H2C * 256 * sizeof(float));
    float* sc1   = (float*)alloc(H1C * sizeof(float));
    float* sh1   = (float*)alloc(H1C * sizeof(float));
    float* sc2   = (float*)alloc(H2C * sizeof(float));
    float* sh2   = (float*)alloc(H2C * sizeof(float));

    cvt_bf16_k<<<(H1C * CIN / 4 + 255) / 256, 256, 0, stream>>>(W1, W1b, H1C * CIN / 4);
    cvt_bf16_k<<<(H2C * H1C / 4 + 255) / 256, 256, 0, stream>>>(W2, W2b, H2C * H1C / 4);
    knn_kernel<<<dim3(M_ / 32, B_), 256, 0, stream>>>(pos, pos_skip, idx, w);
    transpose_x<<<dim3(N_ / 32, C_ / 32, B_), 256, 0, stream>>>(x, xT);
    feats_skip<<<dim3(M_ / 32, CSK / 32, B_), 256, 0, stream>>>(x_skip, Fsk);
    gemm1<<<2048, 256, 0, stream>>>(W1b, xT, Fsk, idx, w, H1, ps1, pq1);
    bn1_final<<<H1C, 256, 0, stream>>>(ps1, pq1, gamma1, beta1, sc1, sh1);
    gemm2<<<NCOL / 256, 512, 0, stream>>>(W2b, H1, sc1, sh1, out, ps2, pq2);
    bn2_final<<<H2C, 256, 0, stream>>>(ps2, pq2, gamma2, beta2, sc2, sh2);
    bn_apply2<<<(int)(((size_t)NCOL * H2C) / 256), 256, 0, stream>>>(out, sc2, sh2);
}